// Round 2
// 246.091 us; speedup vs baseline: 1.0093x; 1.0093x over previous
//
#include <hip/hip_runtime.h>

// HyperConv: y[b,o,t] = sum_{i<3} sum_{c<16} x[b,c,t+8-4i] * w_b[i*16+c][o]
// w_b = LeakyReLU(p[b]@W1 + b1) @ W2 + b2, reshaped [48][16].
//
// R1: latency-bound fix. Baseline exposed HBM latency (VALUBusy 28%,
// 2.3 TB/s) because in-flight loads were VGPR-limited. Now x rows are
// async-staged via global_load_lds (zero VGPR per outstanding load) into a
// 4-buffer rolling pipeline (prefetch distance 3) with raw s_barrier +
// counted vmcnt (NEVER __syncthreads in the loop: it drains vmcnt(0)).
// y stores are nontemporal so writes don't evict x from L3.
// R2: compile fix — nontemporal store needs a clang ext_vector type,
// HIP's float4 struct is rejected by __builtin_nontemporal_store.

#define NB 32
#define IN_CH 16
#define OUT_CH 16
#define KW 3
#define DIL 4
#define COND 8
#define T_OUT 65536
#define PADT 8
#define XT (T_OUT + PADT)            // 65544 floats, row stride of x
#define W2COLS (IN_CH * OUT_CH * KW) // 768
#define TPB 256
#define TPT 4                        // t-positions per thread
#define T_PER_BLOCK (TPB * TPT)      // 1024
#define BLOCKS_PER_B (T_OUT / T_PER_BLOCK) // 64
#define ROWF (T_PER_BLOCK + PADT)    // 1032 floats staged per channel row
#define NBUF 4                       // rolling LDS buffers (distance-3 prefetch)

typedef const __attribute__((address_space(1))) void* gvp;
typedef __attribute__((address_space(3))) void* svp;
typedef float f32x4 __attribute__((ext_vector_type(4)));

// Stage one 1032-float channel row into LDS.
// Wave w loads 64 lanes x 16B at byte offset w*1024 (linear dest = base+lane*16,
// matching global_load_lds's wave-uniform-base semantics). Wave 0 lanes 0..1
// load the 8-float halo tail. => 1 vmem op/row/wave (2 for wave 0).
__device__ __forceinline__ void stage_row(const float* __restrict__ g,
                                          float* l, int wid, int lane)
{
    __builtin_amdgcn_global_load_lds((gvp)(g + wid * 256 + lane * 4),
                                     (svp)(l + wid * 256), 16, 0, 0);
    if (wid == 0 && lane < 2)
        __builtin_amdgcn_global_load_lds((gvp)(g + 1024 + lane * 4),
                                         (svp)(l + 1024), 16, 0, 0);
}

// One channel-row's contribution: 3 taps x 16 outputs x 4 t-positions = 192 FMA.
// xrow reads: 3 conflict-free ds_read_b128 (lane-contiguous);
// weight reads: same-address broadcast (no bank conflicts).
__device__ __forceinline__ void compute_row(const float* __restrict__ xrow,
                                            const float* __restrict__ w_lds,
                                            int c, float4* acc, int tid)
{
    const float4 l0 = *(const float4*)(xrow + tid * 4);      // tap i=2 (+0)
    const float4 l1 = *(const float4*)(xrow + tid * 4 + 4);  // tap i=1 (+4)
    const float4 l2 = *(const float4*)(xrow + tid * 4 + 8);  // tap i=0 (+8)
    const float4 vs[KW] = {l2, l1, l0};                      // vs[i]: offset 8-4i
#pragma unroll
    for (int i = 0; i < KW; ++i) {
        const float4 v = vs[i];
        const float* wrow = w_lds + (i * IN_CH + c) * OUT_CH;
#pragma unroll
        for (int og = 0; og < 4; ++og) {
            const float4 wv = *(const float4*)(wrow + og * 4);
            float4* a = acc + og * 4;
            a[0].x += v.x * wv.x; a[0].y += v.y * wv.x;
            a[0].z += v.z * wv.x; a[0].w += v.w * wv.x;
            a[1].x += v.x * wv.y; a[1].y += v.y * wv.y;
            a[1].z += v.z * wv.y; a[1].w += v.w * wv.y;
            a[2].x += v.x * wv.z; a[2].y += v.y * wv.z;
            a[2].z += v.z * wv.z; a[2].w += v.w * wv.z;
            a[3].x += v.x * wv.w; a[3].y += v.y * wv.w;
            a[3].z += v.z * wv.w; a[3].w += v.w * wv.w;
        }
    }
}

__global__ __launch_bounds__(TPB)
void hyperconv_kernel(const float* __restrict__ x,
                      const float* __restrict__ p,
                      const float* __restrict__ W1,
                      const float* __restrict__ b1,
                      const float* __restrict__ W2,
                      const float* __restrict__ b2,
                      float* __restrict__ y)
{
    __shared__ __align__(16) float xbuf[NBUF][ROWF];  // 16.1 KiB
    __shared__ float h_lds[IN_CH];
    __shared__ __align__(16) float w_lds[W2COLS];     // 3 KiB

    const int tid    = threadIdx.x;
    const int wid    = tid >> 6;
    const int lane   = tid & 63;
    const int b      = blockIdx.x / BLOCKS_PER_B;
    const int tchunk = blockIdx.x % BLOCKS_PER_B;
    const int t0b    = tchunk * T_PER_BLOCK;

    const float* xrb = x + (size_t)b * IN_CH * XT + t0b;

    // Kick off rows 0..2 immediately (latency overlaps the hypernet phase).
    stage_row(xrb + 0 * XT, xbuf[0], wid, lane);
    stage_row(xrb + 1 * XT, xbuf[1], wid, lane);
    stage_row(xrb + 2 * XT, xbuf[2], wid, lane);

    // ---- hypernetwork: h = LeakyReLU(p[b] @ W1 + b1) ----
    if (tid < IN_CH) {
        float acc = b1[tid];
#pragma unroll
        for (int j = 0; j < COND; ++j)
            acc += p[b * COND + j] * W1[j * IN_CH + tid];
        h_lds[tid] = acc > 0.f ? acc : 0.2f * acc;
    }
    __syncthreads();

    // ---- w = h @ W2 + b2 : 768 entries, 3 per thread ----
#pragma unroll
    for (int r = 0; r < 3; ++r) {
        const int n = tid * 3 + r;
        float acc = b2[n];
#pragma unroll
        for (int c = 0; c < IN_CH; ++c)
            acc += h_lds[c] * W2[c * W2COLS + n];
        w_lds[n] = acc;
    }
    __syncthreads();   // drains vmcnt(0): rows 0..2 resident, clean baseline

    float4 acc[OUT_CH];
#pragma unroll
    for (int o = 0; o < OUT_CH; ++o) acc[o] = make_float4(0.f, 0.f, 0.f, 0.f);

    // ---- main pipeline: compute row c while rows c+1..c+3 are in flight ----
    // Buffer safety: stage(c+3) targets xbuf[(c+3)&3] == xbuf[(c-1)&3], whose
    // readers all passed the trailing barrier of iteration c-1.
    for (int c = 0; c < 13; ++c) {
        __builtin_amdgcn_sched_barrier(0);
        stage_row(xrb + (c + 3) * XT, xbuf[(c + 3) & 3], wid, lane);
        // wait own loads for row c: allow rows c+1..c+3 in flight
        if (wid == 0) asm volatile("s_waitcnt vmcnt(6)" ::: "memory");
        else          asm volatile("s_waitcnt vmcnt(3)" ::: "memory");
        __builtin_amdgcn_s_barrier();            // all waves' row-c data landed
        __builtin_amdgcn_sched_barrier(0);
        compute_row(xbuf[c & 3], w_lds, c, acc, tid);
        __builtin_amdgcn_sched_barrier(0);
        __builtin_amdgcn_s_barrier();            // readers done before overwrite
    }
    // ---- tail: rows 13..15 already issued, drain once, no more LDS writes ----
    asm volatile("s_waitcnt vmcnt(0)" ::: "memory");
    __builtin_amdgcn_s_barrier();
    __builtin_amdgcn_sched_barrier(0);
    compute_row(xbuf[13 & 3], w_lds, 13, acc, tid);
    compute_row(xbuf[14 & 3], w_lds, 14, acc, tid);
    compute_row(xbuf[15 & 3], w_lds, 15, acc, tid);

    // ---- store: nontemporal so 131 MB of y doesn't evict x from L3 ----
    float* yb = y + (size_t)b * OUT_CH * T_OUT + t0b + tid * TPT;
#pragma unroll
    for (int o = 0; o < OUT_CH; ++o) {
        const float4 a = acc[o];
        f32x4 v = {a.x, a.y, a.z, a.w};
        __builtin_nontemporal_store(v, (f32x4*)(yb + o * T_OUT));
    }
}

extern "C" void kernel_launch(void* const* d_in, const int* in_sizes, int n_in,
                              void* d_out, int out_size, void* d_ws, size_t ws_size,
                              hipStream_t stream) {
    const float* x  = (const float*)d_in[0];
    const float* p  = (const float*)d_in[1];
    const float* W1 = (const float*)d_in[2];
    const float* b1 = (const float*)d_in[3];
    const float* W2 = (const float*)d_in[4];
    const float* b2 = (const float*)d_in[5];
    float* y = (float*)d_out;

    dim3 grid(NB * BLOCKS_PER_B);   // 2048 blocks
    dim3 block(TPB);
    hyperconv_kernel<<<grid, block, 0, stream>>>(x, p, W1, b1, W2, b2, y);
}